// Round 1
// baseline (1558.653 us; speedup 1.0000x reference)
//
#include <hip/hip_runtime.h>

// Problem constants (fixed by setup_inputs)
#define BB 32
#define CIN 96
#define TT 288
#define VV 25
#define SS 3
#define COUT 96
#define O_TOT (SS*COUT)        // 288
#define WSZ 5
#define PADT 2
#define BN_EPS 1e-5f
#define TV (TT*VV)             // 7200
#define NPOS (BB*TT)           // 9216
#define ELEMS (BB*COUT*TV)     // 22118400
#define VP 28                  // padded m-dim for A tiles (float-quad blocking)

// ---------------------------------------------------------------------------
// K1: fused 1x1 conv + graph (A) contraction, one (b,t) position per block.
//   y[o,n] = sum_i w[o,i] * x[b,i,t,n] + cb[o]        (o in [0,288))
//   z[c,m] = sum_s sum_n y[s*96+c, n] * A[s,n,m]
// ---------------------------------------------------------------------------
__global__ __launch_bounds__(256) void k1_conv_graph(
    const float* __restrict__ x, const float* __restrict__ A,
    const float* __restrict__ w, const float* __restrict__ cb,
    float* __restrict__ z)
{
    __shared__ float xs[CIN*VV];      // 2400 floats = 9.6 KB
    __shared__ float ys[O_TOT*VV];    // 7200 floats = 28.8 KB
    __shared__ float As[SS*VV*VP];    // 2100 floats = 8.4 KB (m padded to 28)

    const int tid = threadIdx.x;
    const int b = blockIdx.x / TT;
    const int t = blockIdx.x % TT;

    // stage x[b,:,t,:] -> xs[i*25+v]
    const float* xp = x + (size_t)b*CIN*TV + (size_t)t*VV;
    for (int e = tid; e < CIN*VV; e += 256) {
        int i = e / VV, v = e - i*VV;
        xs[e] = xp[(size_t)i*TV + v];
    }
    // stage A (padded): As[s][n][mm]
    for (int e = tid; e < SS*VV*VP; e += 256) {
        int mm = e % VP;
        int sn = e / VP;               // s*25+n
        As[e] = (mm < VV) ? A[sn*VV + mm] : 0.0f;
    }
    __syncthreads();

    // phase B: each thread computes y for an o-quad {ob, ob+72, ob+144, ob+216} at one n
    for (int e = tid; e < (O_TOT/4)*VV; e += 256) {   // 1800 units
        int ob = e / VV;
        int n  = e - ob*VV;
        float a0 = 0.f, a1 = 0.f, a2 = 0.f, a3 = 0.f;
        const float* w0 = w + (size_t)(ob      )*CIN;
        const float* w1 = w + (size_t)(ob +  72)*CIN;
        const float* w2 = w + (size_t)(ob + 144)*CIN;
        const float* w3 = w + (size_t)(ob + 216)*CIN;
        #pragma unroll 8
        for (int i = 0; i < CIN; ++i) {
            float xv = xs[i*VV + n];
            a0 = fmaf(w0[i], xv, a0);
            a1 = fmaf(w1[i], xv, a1);
            a2 = fmaf(w2[i], xv, a2);
            a3 = fmaf(w3[i], xv, a3);
        }
        ys[(ob      )*VV + n] = a0 + cb[ob      ];
        ys[(ob +  72)*VV + n] = a1 + cb[ob +  72];
        ys[(ob + 144)*VV + n] = a2 + cb[ob + 144];
        ys[(ob + 216)*VV + n] = a3 + cb[ob + 216];
    }
    __syncthreads();

    // phase C: z[c,m] with m-quad blocking (7 quads cover padded 28)
    float* zp = z + (size_t)b*COUT*TV + (size_t)t*VV;
    for (int u = tid; u < COUT*7; u += 256) {         // 672 units
        int c  = u / 7;
        int mg = (u - c*7) * 4;
        float acc0 = 0.f, acc1 = 0.f, acc2 = 0.f, acc3 = 0.f;
        #pragma unroll
        for (int s = 0; s < SS; ++s) {
            const float* yrow = ys + (s*COUT + c)*VV;
            const float* arow = As + s*VV*VP;
            #pragma unroll
            for (int n = 0; n < VV; ++n) {
                float yv = yrow[n];
                const float* ap = arow + n*VP + mg;
                acc0 = fmaf(yv, ap[0], acc0);
                acc1 = fmaf(yv, ap[1], acc1);
                acc2 = fmaf(yv, ap[2], acc2);
                acc3 = fmaf(yv, ap[3], acc3);
            }
        }
        size_t zb = (size_t)c*TV + mg;
        zp[zb] = acc0;
        if (mg + 1 < VV) zp[zb + 1] = acc1;
        if (mg + 2 < VV) zp[zb + 2] = acc2;
        if (mg + 3 < VV) zp[zb + 3] = acc3;
    }
}

// ---------------------------------------------------------------------------
// K2: window-5 temporal average per (b,c); writes pre-BN value to outp,
//     accumulates per-channel sum / sumsq via one atomicAdd pair per block.
// ---------------------------------------------------------------------------
__global__ __launch_bounds__(256) void k2_window_stats(
    const float* __restrict__ z, float* __restrict__ outp,
    float* __restrict__ ssum, float* __restrict__ ssq)
{
    __shared__ float zs[TV];   // 28.8 KB
    __shared__ float red[8];
    const int tid = threadIdx.x;
    const int b = blockIdx.x / COUT;
    const int c = blockIdx.x % COUT;
    const float* zp = z    + (size_t)(b*COUT + c)*TV;
    float*       op = outp + (size_t)(b*COUT + c)*TV;

    for (int e = tid; e < TV; e += 256) zs[e] = zp[e];
    __syncthreads();

    float ls = 0.f, ls2 = 0.f;
    for (int e = tid; e < TV; e += 256) {
        int t = e / VV, v = e - t*VV;
        float acc = 0.f;
        #pragma unroll
        for (int dt = -PADT; dt <= PADT; ++dt) {
            int tt = t + dt;
            if (tt >= 0 && tt < TT) acc += zs[tt*VV + v];
        }
        acc *= (1.0f / WSZ);
        op[e] = acc;
        ls  += acc;
        ls2 += acc * acc;
    }

    // wave reduce (64 lanes) then cross-wave via LDS
    #pragma unroll
    for (int off = 32; off > 0; off >>= 1) {
        ls  += __shfl_down(ls,  off, 64);
        ls2 += __shfl_down(ls2, off, 64);
    }
    int lane = tid & 63, wid = tid >> 6;
    if (lane == 0) { red[wid*2] = ls; red[wid*2 + 1] = ls2; }
    __syncthreads();
    if (tid == 0) {
        float s  = red[0] + red[2] + red[4] + red[6];
        float s2 = red[1] + red[3] + red[5] + red[7];
        atomicAdd(&ssum[c], s);
        atomicAdd(&ssq[c],  s2);
    }
}

// ---------------------------------------------------------------------------
// K3: per-channel scale/bias from accumulated stats
// ---------------------------------------------------------------------------
__global__ void k3_finalize(const float* __restrict__ ssum, const float* __restrict__ ssq,
                            const float* __restrict__ gamma, const float* __restrict__ beta,
                            float* __restrict__ scale, float* __restrict__ bias)
{
    int c = threadIdx.x;
    if (c < COUT) {
        const float invN = 1.0f / (float)(BB * TV);
        float mean = ssum[c] * invN;
        float var  = ssq[c] * invN - mean * mean;
        float inv  = rsqrtf(var + BN_EPS);
        float sc   = gamma[c] * inv;
        scale[c] = sc;
        bias[c]  = beta[c] - mean * sc;
    }
}

// ---------------------------------------------------------------------------
// K4: in-place normalize + ReLU on d_out (float4)
// ---------------------------------------------------------------------------
__global__ __launch_bounds__(256) void k4_norm_relu(
    float4* __restrict__ out, const float* __restrict__ scale, const float* __restrict__ bias)
{
    size_t i4 = (size_t)blockIdx.x * 256 + threadIdx.x;
    if (i4 < (size_t)ELEMS / 4) {
        int c = (int)((i4 * 4 / TV) % COUT);   // TV % 4 == 0 -> c uniform within float4
        float sc = scale[c], bi = bias[c];
        float4 v = out[i4];
        v.x = fmaxf(fmaf(v.x, sc, bi), 0.f);
        v.y = fmaxf(fmaf(v.y, sc, bi), 0.f);
        v.z = fmaxf(fmaf(v.z, sc, bi), 0.f);
        v.w = fmaxf(fmaf(v.w, sc, bi), 0.f);
        out[i4] = v;
    }
}

extern "C" void kernel_launch(void* const* d_in, const int* in_sizes, int n_in,
                              void* d_out, int out_size, void* d_ws, size_t ws_size,
                              hipStream_t stream) {
    const float* x      = (const float*)d_in[0];
    const float* A      = (const float*)d_in[1];
    const float* conv_w = (const float*)d_in[2];
    const float* conv_b = (const float*)d_in[3];
    const float* gamma  = (const float*)d_in[4];
    const float* beta   = (const float*)d_in[5];
    float* out = (float*)d_out;

    // workspace layout: z (ELEMS floats) | ssum (96) | ssq (96) | scale (96) | bias (96)
    float* z     = (float*)d_ws;
    float* ssum  = z + ELEMS;
    float* ssq   = ssum + COUT;
    float* scale = ssq  + COUT;
    float* bias  = scale + COUT;

    hipMemsetAsync(ssum, 0, 2 * COUT * sizeof(float), stream);

    k1_conv_graph<<<dim3(NPOS), dim3(256), 0, stream>>>(x, A, conv_w, conv_b, z);
    k2_window_stats<<<dim3(BB*COUT), dim3(256), 0, stream>>>(z, out, ssum, ssq);
    k3_finalize<<<dim3(1), dim3(128), 0, stream>>>(ssum, ssq, gamma, beta, scale, bias);
    k4_norm_relu<<<dim3(ELEMS/4/256), dim3(256), 0, stream>>>((float4*)out, scale, bias);
}

// Round 2
// 448.181 us; speedup vs baseline: 3.4777x; 3.4777x over previous
//
#include <hip/hip_runtime.h>
#include <hip/hip_bf16.h>

// Problem constants
#define BB 32
#define CIN 96
#define TT 288
#define VV 25
#define SS 3
#define COUT 96
#define WSZ 5
#define BN_EPS 1e-5f
#define TV (TT*VV)              // 7200
#define ELEMS (BB*COUT*TV)      // 22118400
#define MK 2400                 // GEMM K = (i,n)
#define GMP 2432                // GEMM M padded (19 x 128), true M = 2400 = (c,m)
#define GN 9216                 // GEMM N = (b,t)

typedef __attribute__((ext_vector_type(8))) short bf16x8;
typedef __attribute__((ext_vector_type(4))) float f32x4;

__device__ __forceinline__ void gload_lds16(const void* g, void* l) {
    __builtin_amdgcn_global_load_lds(
        (const __attribute__((address_space(1))) unsigned int*)g,
        (__attribute__((address_space(3))) unsigned int*)l, 16, 0, 0);
}

// ---------------------------------------------------------------------------
// wprep: W2b[row=(c,mv)][kk=(i,n)] = sum_s w[s*96+c, i] * A[s, n, mv]  (bf16)
// rows 2400..2431 zero-padded. One block per row.
// ---------------------------------------------------------------------------
__global__ __launch_bounds__(256) void wprep(const float* __restrict__ w,
                                             const float* __restrict__ A,
                                             __hip_bfloat16* __restrict__ W2b)
{
    __shared__ float Ash[SS*VV*VV];   // 1875 floats
    __shared__ float wsh[SS*CIN];     // 288 floats
    const int tid = threadIdx.x;
    const int row = blockIdx.x;
    __hip_bfloat16* orow = W2b + (size_t)row * MK;
    if (row >= 2400) {
        for (int kk = tid; kk < MK; kk += 256) orow[kk] = __float2bfloat16(0.0f);
        return;
    }
    const int c = row / VV, mv = row - c*VV;
    for (int e = tid; e < SS*VV*VV; e += 256) Ash[e] = A[e];
    for (int e = tid; e < SS*CIN; e += 256) {
        int s = e / CIN, i = e - s*CIN;
        wsh[e] = w[(s*COUT + c)*CIN + i];
    }
    __syncthreads();
    for (int kk = tid; kk < MK; kk += 256) {
        int i = kk / VV, n = kk - i*VV;
        float v = 0.f;
        #pragma unroll
        for (int s = 0; s < SS; ++s)
            v = fmaf(wsh[s*CIN + i], Ash[(s*VV + n)*VV + mv], v);
        orow[kk] = __float2bfloat16(v);
    }
}

// zbias[row=(c,mv)] = sum_s cb[s*96+c] * sum_n A[s,n,mv]
__global__ void zbias_k(const float* __restrict__ A, const float* __restrict__ cb,
                        float* __restrict__ zbias)
{
    int row = blockIdx.x * 256 + threadIdx.x;
    if (row < 2400) {
        int c = row / VV, mv = row - c*VV;
        float v = 0.f;
        #pragma unroll
        for (int s = 0; s < SS; ++s) {
            float sa = 0.f;
            #pragma unroll
            for (int n = 0; n < VV; ++n) sa += A[(s*VV + n)*VV + mv];
            v = fmaf(cb[s*COUT + c], sa, v);
        }
        zbias[row] = v;
    }
}

// ---------------------------------------------------------------------------
// xprep: Xb[(b*288+t)][(i*25+v)] = bf16(x[b][i][t][v])   (transpose + convert)
// ---------------------------------------------------------------------------
__global__ __launch_bounds__(256) void xprep(const float* __restrict__ x,
                                             __hip_bfloat16* __restrict__ Xb)
{
    int idx = blockIdx.x * 256 + threadIdx.x;      // grid sized exactly ELEMS/256
    int b   = idx / (CIN*TV);
    int rem = idx - b*CIN*TV;
    int i   = rem / TV;
    int e   = rem - i*TV;
    int t   = e / VV, v = e - t*VV;
    Xb[(size_t)(b*TT + t)*MK + i*VV + v] = __float2bfloat16(x[idx]);
}

// ---------------------------------------------------------------------------
// GEMM: z = W2b[M=2432,K=2400] x Xb[N=9216,K=2400]^T + zbias, written directly
// into out[b][c][t][v] (raw pre-window z). 128x128 tile, BK=32, 4 waves,
// global_load_lds width-16 staging, 16x16x32 bf16 MFMA, 4x4 tiles/wave.
// ---------------------------------------------------------------------------
__global__ __launch_bounds__(256) void gemm_zb(
    const __hip_bfloat16* __restrict__ W2b,
    const __hip_bfloat16* __restrict__ Xb,
    const float* __restrict__ zbias,
    float* __restrict__ out)
{
    __shared__ __hip_bfloat16 As[128*32];   // 8 KB, [m][k]
    __shared__ __hip_bfloat16 Bs[128*32];   // 8 KB, [n][k]
    const int tid  = threadIdx.x;
    const int lane = tid & 63;
    const int wave = tid >> 6;
    const int m0 = blockIdx.x * 128;
    const int n0 = blockIdx.y * 128;
    const int m_off = (wave & 1) * 64;
    const int n_off = (wave >> 1) * 64;

    // staging addresses: 512 chunks of 16B per matrix, 2 per thread
    const int r0 = tid >> 2;            // 0..63
    const int kc = (tid & 3) * 8;       // k offset in elements
    const __hip_bfloat16* gA0 = W2b + (size_t)(m0 + r0) * MK + kc;
    const __hip_bfloat16* gA1 = gA0 + (size_t)64 * MK;
    const __hip_bfloat16* gB0 = Xb  + (size_t)(n0 + r0) * MK + kc;
    const __hip_bfloat16* gB1 = gB0 + (size_t)64 * MK;
    __hip_bfloat16* lA0 = As + tid*8;
    __hip_bfloat16* lA1 = As + tid*8 + 2048;
    __hip_bfloat16* lB0 = Bs + tid*8;
    __hip_bfloat16* lB1 = Bs + tid*8 + 2048;

    f32x4 acc[4][4] = {};
    const int arow = (m_off + (lane & 15))*32 + (lane >> 4)*8;  // elem offset
    const int brow = (n_off + (lane & 15))*32 + (lane >> 4)*8;

    for (int k = 0; k < MK; k += 32) {
        gload_lds16(gA0, lA0);
        gload_lds16(gA1, lA1);
        gload_lds16(gB0, lB0);
        gload_lds16(gB1, lB1);
        gA0 += 32; gA1 += 32; gB0 += 32; gB1 += 32;
        __syncthreads();
        bf16x8 af[4], bfr[4];
        #pragma unroll
        for (int mt = 0; mt < 4; ++mt) af[mt]  = *(const bf16x8*)&As[arow + mt*512];
        #pragma unroll
        for (int nt = 0; nt < 4; ++nt) bfr[nt] = *(const bf16x8*)&Bs[brow + nt*512];
        #pragma unroll
        for (int mt = 0; mt < 4; ++mt)
            #pragma unroll
            for (int nt = 0; nt < 4; ++nt)
                acc[mt][nt] = __builtin_amdgcn_mfma_f32_16x16x32_bf16(
                    af[mt], bfr[nt], acc[mt][nt], 0, 0, 0);
        __syncthreads();
    }

    // epilogue: C/D layout col=lane&15, row=(lane>>4)*4+r; scatter to [b][c][t][v]
    const int colb = n0 + n_off + (lane & 15);
    #pragma unroll
    for (int nt = 0; nt < 4; ++nt) {
        int col = colb + nt*16;
        int b = col / TT, t = col - b*TT;
        float* obase = out + ((size_t)b*COUT*TT + t) * VV;
        #pragma unroll
        for (int mt = 0; mt < 4; ++mt) {
            int rowb = m0 + m_off + mt*16 + (lane >> 4)*4;
            #pragma unroll
            for (int r = 0; r < 4; ++r) {
                int row = rowb + r;
                if (row < 2400) {
                    int c = row / VV, v = row - c*VV;
                    obase[(size_t)c*TV + v] = acc[mt][nt][r] + zbias[row];
                }
            }
        }
    }
}

// ---------------------------------------------------------------------------
// k2: per (b,c) slab — window-5 temporal average IN PLACE (slab staged in LDS)
//     + per-channel sum/sumsq atomics.
// ---------------------------------------------------------------------------
__global__ __launch_bounds__(256) void k2_window_stats(
    float* __restrict__ out, float* __restrict__ ssum, float* __restrict__ ssq)
{
    __shared__ float zs[TV];    // 28.8 KB
    __shared__ float red[8];
    const int tid = threadIdx.x;
    const int b = blockIdx.x / COUT;
    const int c = blockIdx.x - b*COUT;
    float* slab = out + (size_t)(b*COUT + c) * TV;

    for (int e = tid; e < TV; e += 256) zs[e] = slab[e];
    __syncthreads();

    float ls = 0.f, ls2 = 0.f;
    for (int e = tid; e < TV; e += 256) {
        int t = e / VV;
        float acc = zs[e];
        if (t >= 1)       acc += zs[e - VV];
        if (t >= 2)       acc += zs[e - 2*VV];
        if (t <= TT-2)    acc += zs[e + VV];
        if (t <= TT-3)    acc += zs[e + 2*VV];
        acc *= (1.0f / WSZ);
        slab[e] = acc;
        ls  += acc;
        ls2 += acc * acc;
    }
    #pragma unroll
    for (int off = 32; off > 0; off >>= 1) {
        ls  += __shfl_down(ls,  off, 64);
        ls2 += __shfl_down(ls2, off, 64);
    }
    int lane = tid & 63, wid = tid >> 6;
    if (lane == 0) { red[wid*2] = ls; red[wid*2+1] = ls2; }
    __syncthreads();
    if (tid == 0) {
        atomicAdd(&ssum[c], red[0] + red[2] + red[4] + red[6]);
        atomicAdd(&ssq[c],  red[1] + red[3] + red[5] + red[7]);
    }
}

__global__ void k3_finalize(const float* __restrict__ ssum, const float* __restrict__ ssq,
                            const float* __restrict__ gamma, const float* __restrict__ beta,
                            float* __restrict__ scale, float* __restrict__ bias)
{
    int c = threadIdx.x;
    if (c < COUT) {
        const float invN = 1.0f / (float)(BB * TV);
        float mean = ssum[c] * invN;
        float var  = ssq[c] * invN - mean * mean;
        float inv  = rsqrtf(var + BN_EPS);
        float sc   = gamma[c] * inv;
        scale[c] = sc;
        bias[c]  = beta[c] - mean * sc;
    }
}

__global__ __launch_bounds__(256) void k4_norm_relu(
    float4* __restrict__ out, const float* __restrict__ scale, const float* __restrict__ bias)
{
    size_t i4 = (size_t)blockIdx.x * 256 + threadIdx.x;   // grid sized exactly
    int c = (int)((i4 * 4 / TV) % COUT);                  // TV%4==0 -> uniform in float4
    float sc = scale[c], bi = bias[c];
    float4 v = out[i4];
    v.x = fmaxf(fmaf(v.x, sc, bi), 0.f);
    v.y = fmaxf(fmaf(v.y, sc, bi), 0.f);
    v.z = fmaxf(fmaf(v.z, sc, bi), 0.f);
    v.w = fmaxf(fmaf(v.w, sc, bi), 0.f);
    out[i4] = v;
}

extern "C" void kernel_launch(void* const* d_in, const int* in_sizes, int n_in,
                              void* d_out, int out_size, void* d_ws, size_t ws_size,
                              hipStream_t stream) {
    const float* x      = (const float*)d_in[0];
    const float* A      = (const float*)d_in[1];
    const float* conv_w = (const float*)d_in[2];
    const float* conv_b = (const float*)d_in[3];
    const float* gamma  = (const float*)d_in[4];
    const float* beta   = (const float*)d_in[5];
    float* out = (float*)d_out;

    // ws layout: zbias(2400 f) | ssum(96) | ssq(96) | scale(96) | bias(96) | Xb bf16 | W2b bf16
    float* zbias = (float*)d_ws;
    float* ssum  = zbias + 2400;
    float* ssq   = ssum + COUT;
    float* scale = ssq  + COUT;
    float* bias  = scale + COUT;
    __hip_bfloat16* Xb  = (__hip_bfloat16*)(bias + COUT);
    __hip_bfloat16* W2b = Xb + (size_t)GN * MK;
    // total: 11136 + 44.24 MB + 11.67 MB = 55.9 MB

    hipMemsetAsync(ssum, 0, 2 * COUT * sizeof(float), stream);

    wprep  <<<dim3(GMP),           dim3(256), 0, stream>>>(conv_w, A, W2b);
    zbias_k<<<dim3(10),            dim3(256), 0, stream>>>(A, conv_b, zbias);
    xprep  <<<dim3(ELEMS/256),     dim3(256), 0, stream>>>(x, Xb);
    gemm_zb<<<dim3(GMP/128, GN/128), dim3(256), 0, stream>>>(W2b, Xb, zbias, out);
    k2_window_stats<<<dim3(BB*COUT), dim3(256), 0, stream>>>(out, ssum, ssq);
    k3_finalize<<<dim3(1), dim3(128), 0, stream>>>(ssum, ssq, gamma, beta, scale, bias);
    k4_norm_relu<<<dim3(ELEMS/4/256), dim3(256), 0, stream>>>((float4*)out, scale, bias);
}